// Round 3
// baseline (294.297 us; speedup 1.0000x reference)
//
#include <hip/hip_runtime.h>

#define NT 64
#define NCOL 1116
#define NLEV 7

typedef float v2f __attribute__((ext_vector_type(2)));

static constexpr float DEC_LO[8] = {-0.010597401784997278f,  0.032883011666982945f,
                                     0.030841381835986965f, -0.18703481171888114f,
                                    -0.02798376941698385f,   0.6308807679295904f,
                                     0.7148465705525415f,    0.23037781330885523f};
static constexpr float DEC_HI[8] = {-0.23037781330885523f,   0.7148465705525415f,
                                    -0.6308807679295904f,   -0.02798376941698385f,
                                     0.18703481171888114f,   0.030841381835986965f,
                                    -0.032883011666982945f, -0.010597401784997278f};
static constexpr float REC_LO[8] = { 0.23037781330885523f,   0.7148465705525415f,
                                     0.6308807679295904f,   -0.02798376941698385f,
                                    -0.18703481171888114f,   0.030841381835986965f,
                                     0.032883011666982945f, -0.010597401784997278f};
static constexpr float REC_HI[8] = {-0.010597401784997278f, -0.032883011666982945f,
                                     0.030841381835986965f,  0.18703481171888114f,
                                    -0.02798376941698385f,  -0.6308807679295904f,
                                     0.7148465705525415f,   -0.23037781330885523f};

static constexpr int ALEN[8] = {1116, 561, 284, 145, 76, 41, 24, 15};
// detail segment offsets, each 16B-aligned, padded for unconditional float4 stores
static constexpr int DOFF[7] = {0, 564, 848, 996, 1072, 1116, 1140};

static __device__ __forceinline__ float softf(float c, float t) {
    float m = fabsf(c) - t;
    return m > 0.0f ? copysignf(m, c) : 0.0f;
}

static __device__ __forceinline__ v2f vfma(float c, v2f v, v2f a) {
#if __has_builtin(__builtin_elementwise_fma)
    return __builtin_elementwise_fma((v2f){c, c}, v, a);
#else
    v2f r; r.x = fmaf(c, v.x, a.x); r.y = fmaf(c, v.y, a.y); return r;
#endif
}

// Forward level: 4 outputs per task. cur/nxt data start at LDS float-index ≡ 2 (mod 4),
// so window start (8t-6) is 16B-aligned. Over-computed outputs read zeroed pad and
// therefore write zeros (pads self-maintain); tail-zero covers the next level's over-read.
template <int L, bool LAST>
static __device__ __forceinline__ void fwd_level(const float* cur, float* nxt, float* dp,
                                                 float thr, int tid) {
    constexpr int nout = ALEN[L + 1];
    constexpr int ntask = (nout + 3) / 4;
    for (int t = tid; t < ntask; t += NT) {
        const float* src = cur + 8 * t - 6;          // 16B aligned
        float4 w0 = *(const float4*)src;
        float4 w1 = *(const float4*)(src + 4);
        float4 w2 = *(const float4*)(src + 8);
        float4 w3 = *(const float4*)(src + 12);
        float w[16] = {w0.x, w0.y, w0.z, w0.w, w1.x, w1.y, w1.z, w1.w,
                       w2.x, w2.y, w2.z, w2.w, w3.x, w3.y, w3.z, w3.w};
        v2f loA = {0.f, 0.f}, loB = {0.f, 0.f}, hiA = {0.f, 0.f}, hiB = {0.f, 0.f};
#pragma unroll
        for (int s = 0; s < 8; ++s) {
            v2f vA = {w[7 - s],  w[9 - s]};          // outputs 4t, 4t+1
            v2f vB = {w[11 - s], w[13 - s]};         // outputs 4t+2, 4t+3
            loA = vfma(DEC_LO[s], vA, loA);
            hiA = vfma(DEC_HI[s], vA, hiA);
            loB = vfma(DEC_LO[s], vB, loB);
            hiB = vfma(DEC_HI[s], vB, hiB);
        }
        if (LAST) {
            loA.x = softf(loA.x, thr); loA.y = softf(loA.y, thr);
            loB.x = softf(loB.x, thr); loB.y = softf(loB.y, thr);
        }
        *(float4*)(dp + 4 * t) = make_float4(softf(hiA.x, thr), softf(hiA.y, thr),
                                             softf(hiB.x, thr), softf(hiB.y, thr));
        *(v2f*)(nxt + 4 * t)     = loA;
        *(v2f*)(nxt + 4 * t + 2) = loB;
    }
    // zero the window over-read region for the next consumer of nxt
    if (tid < 14) nxt[4 * ntask + tid] = 0.0f;
}

// Inverse level: 4 output pairs (8 samples) per task.
// y[2m]   = RL0*ca[m+3]+RL2*ca[m+2]+RL4*ca[m+1]+RL6*ca[m] + (RH even)*cd
// y[2m+1] = RL1*ca[m+3]+RL3*ca[m+2]+RL5*ca[m+1]+RL7*ca[m] + (RH odd)*cd
template <int L, bool FINAL>
static __device__ __forceinline__ void inv_level(const float* ca, const float* dp,
                                                 float* y, int tid) {
    constexpr int M = ALEN[L + 1];
    constexpr int npair = M - 3;
    constexpr int ntask = (npair + 3) / 4;
    for (int t = tid; t < ntask; t += NT) {
        const float* cap = ca + 4 * t;
        float2 a01 = *(const float2*)cap;
        float2 a23 = *(const float2*)(cap + 2);
        float2 a45 = *(const float2*)(cap + 4);
        float2 a67 = *(const float2*)(cap + 6);
        float4 dq0 = *(const float4*)(dp + 4 * t);       // dp + 4t is 16B aligned
        float4 dq1 = *(const float4*)(dp + 4 * t + 4);
        float aw[8] = {a01.x, a01.y, a23.x, a23.y, a45.x, a45.y, a67.x, a67.y};
        float dw[8] = {dq0.x, dq0.y, dq0.z, dq0.w, dq1.x, dq1.y, dq1.z, dq1.w};
        v2f yeA = {0.f, 0.f}, yoA = {0.f, 0.f}, yeB = {0.f, 0.f}, yoB = {0.f, 0.f};
#pragma unroll
        for (int k = 0; k < 4; ++k) {
            v2f vaA = {aw[3 - k], aw[4 - k]};   // ca[m+3-k], m = 4t, 4t+1
            v2f vdA = {dw[3 - k], dw[4 - k]};
            v2f vaB = {aw[5 - k], aw[6 - k]};   // m = 4t+2, 4t+3
            v2f vdB = {dw[5 - k], dw[6 - k]};
            yeA = vfma(REC_LO[2 * k],     vaA, yeA);
            yoA = vfma(REC_LO[2 * k + 1], vaA, yoA);
            yeA = vfma(REC_HI[2 * k],     vdA, yeA);
            yoA = vfma(REC_HI[2 * k + 1], vdA, yoA);
            yeB = vfma(REC_LO[2 * k],     vaB, yeB);
            yoB = vfma(REC_LO[2 * k + 1], vaB, yoB);
            yeB = vfma(REC_HI[2 * k],     vdB, yeB);
            yoB = vfma(REC_HI[2 * k + 1], vdB, yoB);
        }
        if (FINAL) {
            *(float4*)(y + 8 * t) = make_float4(yeA.x, yoA.x, yeA.y, yoA.y);
            if (4 * t + 2 < npair)
                *(float4*)(y + 8 * t + 4) = make_float4(yeB.x, yoB.x, yeB.y, yoB.y);
        } else {
            *(v2f*)(y + 8 * t)     = (v2f){yeA.x, yoA.x};
            *(v2f*)(y + 8 * t + 2) = (v2f){yeA.y, yoA.y};
            *(v2f*)(y + 8 * t + 4) = (v2f){yeB.x, yoB.x};
            *(v2f*)(y + 8 * t + 6) = (v2f){yeB.y, yoB.y};
        }
    }
}

__global__ __launch_bounds__(NT)
void wavelet_kernel(const float* __restrict__ x,
                    const float* __restrict__ thr_ptr,
                    float* __restrict__ out) {
    __shared__ __align__(16) float A[1140];  // 6 pre-pad | 1116 | >=14 post
    __shared__ __align__(16) float B[588];   // 6 pre-pad | data | slack
    __shared__ __align__(16) float D[1156];  // thresholded detail segments

    const int tid = threadIdx.x;
    const float thr = fmaxf(thr_ptr[0], 0.01f);
    float* a0 = A + 6;   // data starts at float-index ≡ 2 (mod 4)
    float* b0 = B + 6;

    {
        const float4* xr = (const float4*)(x + (size_t)blockIdx.x * NCOL);
        for (int i = tid; i < NCOL / 4; i += NT) {
            float4 v = xr[i];
            *(v2f*)(a0 + 4 * i)     = (v2f){v.x, v.y};
            *(v2f*)(a0 + 4 * i + 2) = (v2f){v.z, v.w};
        }
        if (tid < 6)  { A[tid] = 0.0f; B[tid] = 0.0f; }
        if (tid < 14) a0[NCOL + tid] = 0.0f;
    }
    __syncthreads();  // single-wave workgroup: compiles to waitcnt only

    fwd_level<0, false>(a0, b0, D + DOFF[0], thr, tid); __syncthreads();
    fwd_level<1, false>(b0, a0, D + DOFF[1], thr, tid); __syncthreads();
    fwd_level<2, false>(a0, b0, D + DOFF[2], thr, tid); __syncthreads();
    fwd_level<3, false>(b0, a0, D + DOFF[3], thr, tid); __syncthreads();
    fwd_level<4, false>(a0, b0, D + DOFF[4], thr, tid); __syncthreads();
    fwd_level<5, false>(b0, a0, D + DOFF[5], thr, tid); __syncthreads();
    fwd_level<6, true >(a0, b0, D + DOFF[6], thr, tid); __syncthreads();  // a7 in b0

    inv_level<6, false>(b0, D + DOFF[6], a0, tid); __syncthreads();
    inv_level<5, false>(a0, D + DOFF[5], b0, tid); __syncthreads();
    inv_level<4, false>(b0, D + DOFF[4], a0, tid); __syncthreads();
    inv_level<3, false>(a0, D + DOFF[3], b0, tid); __syncthreads();
    inv_level<2, false>(b0, D + DOFF[2], a0, tid); __syncthreads();
    inv_level<1, false>(a0, D + DOFF[1], b0, tid); __syncthreads();

    float* orow = out + (size_t)blockIdx.x * NCOL;
    inv_level<0, true>(b0, D + DOFF[0], orow, tid);
}

extern "C" void kernel_launch(void* const* d_in, const int* in_sizes, int n_in,
                              void* d_out, int out_size, void* d_ws, size_t ws_size,
                              hipStream_t stream) {
    const float* x = (const float*)d_in[0];
    const float* thr = (const float*)d_in[1];
    float* out = (float*)d_out;
    const int nrow = in_sizes[0] / NCOL;
    hipLaunchKernelGGL(wavelet_kernel, dim3(nrow), dim3(NT), 0, stream, x, thr, out);
}